// Round 1
// baseline (491.694 us; speedup 1.0000x reference)
//
#include <hip/hip_runtime.h>
#include <hip/hip_cooperative_groups.h>

namespace cg = cooperative_groups;

// Segment-normalized chunked linear, FUSED single cooperative dispatch:
//   phase 0: stage slices->LDS, zero LDS hist, atomicExch-zero global seg_abs
//   phase 1: stream x (HBM), per-block LDS histogram of sum|y| per segment
//   grid.sync()  -> zeros ordered before flushes
//   flush LDS hist -> global seg_abs (few atomics/block)
//   grid.sync()  -> all seg_abs final
//   phase 2: re-stream x (L3-resident), y = xW^T, scale by 1/seg_abs, NT-store
// Removes: memset dispatch, 2nd kernel launch, duplicate slices staging.
// HBM floor ~268 MB -> ~45 us of unavoidable traffic.

#define NSEG  4096
#define BLK   256
#define RPT   16
#define BATCH 8
#define CHUNK (BLK * RPT)         // 4096 rows per chunk
#define NCU   256                 // MI355X

typedef float v4 __attribute__((ext_vector_type(4)));

__device__ __forceinline__ float absrow(v4 v, const float* w) {
    float y0 = fabsf(v.x * w[0]  + v.y * w[1]  + v.z * w[2]  + v.w * w[3]);
    float y1 = fabsf(v.x * w[4]  + v.y * w[5]  + v.z * w[6]  + v.w * w[7]);
    float y2 = fabsf(v.x * w[8]  + v.y * w[9]  + v.z * w[10] + v.w * w[11]);
    float y3 = fabsf(v.x * w[12] + v.y * w[13] + v.z * w[14] + v.w * w[15]);
    return (y0 + y1) + (y2 + y3);
}

__global__ __launch_bounds__(BLK, 4) void seg_fused(
    const v4* __restrict__ x, const int* __restrict__ slices,
    const float* __restrict__ W, float* __restrict__ seg_abs,
    v4* __restrict__ out, int n, int nchunks)
{
    // exactly 32 KB static LDS (sl[NSEG] is provably never read:
    // binary-search mid <= NSEG-1, walk reads sl[s+1] with s <= NSEG-2)
    __shared__ int   sl[NSEG];
    __shared__ float hist[NSEG];
#pragma unroll
    for (int i = threadIdx.x; i < NSEG; i += BLK) { sl[i] = slices[i]; hist[i] = 0.0f; }

    // zero global hist; atomic so it is coherent with the later atomicAdds
    for (int i = blockIdx.x * BLK + threadIdx.x; i < NSEG; i += gridDim.x * BLK)
        atomicExch(&seg_abs[i], 0.0f);

    float w[16];
#pragma unroll
    for (int i = 0; i < 16; ++i) w[i] = W[i];
    __syncthreads();

    // ---------------- phase 1: per-block LDS histogram ----------------
    for (int c = blockIdx.x; c < nchunks; c += gridDim.x) {
        const int base = c * CHUNK + threadIdx.x;
        int lo = 0, hi = NSEG;
        {
            int r0 = (base < n) ? base : (n - 1);
            while (hi - lo > 1) { int mid = (lo + hi) >> 1; if (sl[mid] <= r0) lo = mid; else hi = mid; }
        }
        int seg = lo;
        float acc = 0.0f;

        const bool full = (base + (RPT - 1) * BLK) < n;
        if (full) {
#pragma unroll
            for (int b = 0; b < RPT / BATCH; ++b) {
                v4 d[BATCH];
#pragma unroll
                for (int j = 0; j < BATCH; ++j)          // 8 loads issue back-to-back
                    d[j] = x[base + (b * BATCH + j) * BLK];
#pragma unroll
                for (int j = 0; j < BATCH; ++j) {
                    int r = base + (b * BATCH + j) * BLK;
                    int s = seg;
                    while (s < NSEG - 1 && sl[s + 1] <= r) ++s;
                    if (s != seg) { atomicAdd(&hist[seg], acc); acc = 0.0f; seg = s; }
                    acc += absrow(d[j], w);
                }
            }
        } else {
            for (int it = 0; it < RPT; ++it) {
                int r = base + it * BLK;
                if (r < n) {
                    int s = seg;
                    while (s < NSEG - 1 && sl[s + 1] <= r) ++s;
                    if (s != seg) { atomicAdd(&hist[seg], acc); acc = 0.0f; seg = s; }
                    acc += absrow(x[r], w);
                }
            }
        }
        if (acc != 0.0f) atomicAdd(&hist[seg], acc);
    }
    __syncthreads();

    cg::grid_group grid = cg::this_grid();
    grid.sync();                       // zeros done everywhere; hists built

    // flush block-local histogram; ~2-3 nonzero bins per chunk on average
#pragma unroll
    for (int i = threadIdx.x; i < NSEG; i += BLK) {
        float h = hist[i];
        if (h != 0.0f) atomicAdd(&seg_abs[i], h);
    }
    grid.sync();                       // all seg_abs final & visible

    // ---------------- phase 2: normalize (x is L3-resident) ----------------
    for (int c = blockIdx.x; c < nchunks; c += gridDim.x) {
        const int base = c * CHUNK + threadIdx.x;
        int lo = 0, hi = NSEG;
        {
            int r0 = (base < n) ? base : (n - 1);
            while (hi - lo > 1) { int mid = (lo + hi) >> 1; if (sl[mid] <= r0) lo = mid; else hi = mid; }
        }
        int seg = lo;
        float inv = 1.0f / seg_abs[seg];

        const bool full = (base + (RPT - 1) * BLK) < n;
        if (full) {
#pragma unroll
            for (int b = 0; b < RPT / BATCH; ++b) {
                v4 d[BATCH];
#pragma unroll
                for (int j = 0; j < BATCH; ++j)
                    d[j] = x[base + (b * BATCH + j) * BLK];
#pragma unroll
                for (int j = 0; j < BATCH; ++j) {
                    int r = base + (b * BATCH + j) * BLK;
                    int s = seg;
                    while (s < NSEG - 1 && sl[s + 1] <= r) ++s;
                    if (s != seg) { seg = s; inv = 1.0f / seg_abs[seg]; }
                    v4 v = d[j], o;
                    o.x = (v.x * w[0]  + v.y * w[1]  + v.z * w[2]  + v.w * w[3])  * inv;
                    o.y = (v.x * w[4]  + v.y * w[5]  + v.z * w[6]  + v.w * w[7])  * inv;
                    o.z = (v.x * w[8]  + v.y * w[9]  + v.z * w[10] + v.w * w[11]) * inv;
                    o.w = (v.x * w[12] + v.y * w[13] + v.z * w[14] + v.w * w[15]) * inv;
                    __builtin_nontemporal_store(o, &out[r]);  // don't evict x from L3
                }
            }
        } else {
            for (int it = 0; it < RPT; ++it) {
                int r = base + it * BLK;
                if (r < n) {
                    int s = seg;
                    while (s < NSEG - 1 && sl[s + 1] <= r) ++s;
                    if (s != seg) { seg = s; inv = 1.0f / seg_abs[seg]; }
                    v4 v = x[r], o;
                    o.x = (v.x * w[0]  + v.y * w[1]  + v.z * w[2]  + v.w * w[3])  * inv;
                    o.y = (v.x * w[4]  + v.y * w[5]  + v.z * w[6]  + v.w * w[7])  * inv;
                    o.z = (v.x * w[8]  + v.y * w[9]  + v.z * w[10] + v.w * w[11]) * inv;
                    o.w = (v.x * w[12] + v.y * w[13] + v.z * w[14] + v.w * w[15]) * inv;
                    __builtin_nontemporal_store(o, &out[r]);
                }
            }
        }
    }
}

// ---------------- fallback: proven two-pass path ----------------
__global__ __launch_bounds__(BLK) void seg_pass1(
    const v4* __restrict__ x, const int* __restrict__ slices,
    const float* __restrict__ W, float* __restrict__ seg_abs, int n)
{
    __shared__ int   sl[NSEG + 1];
    __shared__ float hist[NSEG];
#pragma unroll
    for (int i = threadIdx.x; i < NSEG + 1; i += BLK) sl[i] = slices[i];
#pragma unroll
    for (int i = threadIdx.x; i < NSEG; i += BLK) hist[i] = 0.0f;
    float w[16];
#pragma unroll
    for (int i = 0; i < 16; ++i) w[i] = W[i];
    __syncthreads();

    const int base = blockIdx.x * CHUNK + threadIdx.x;
    int lo = 0, hi = NSEG;
    {
        int r0 = (base < n) ? base : (n - 1);
        while (hi - lo > 1) { int mid = (lo + hi) >> 1; if (sl[mid] <= r0) lo = mid; else hi = mid; }
    }
    int seg = lo;
    float acc = 0.0f;
    for (int it = 0; it < RPT; ++it) {
        int r = base + it * BLK;
        if (r < n) {
            int s = seg;
            while (s < NSEG - 1 && sl[s + 1] <= r) ++s;
            if (s != seg) { atomicAdd(&hist[seg], acc); acc = 0.0f; seg = s; }
            acc += absrow(x[r], w);
        }
    }
    if (acc != 0.0f) atomicAdd(&hist[seg], acc);
    __syncthreads();
#pragma unroll
    for (int i = threadIdx.x; i < NSEG; i += BLK) {
        float h = hist[i];
        if (h != 0.0f) atomicAdd(&seg_abs[i], h);
    }
}

__global__ __launch_bounds__(BLK) void seg_pass2(
    const v4* __restrict__ x, const int* __restrict__ slices,
    const float* __restrict__ W, const float* __restrict__ seg_abs,
    v4* __restrict__ out, int n)
{
    __shared__ int sl[NSEG + 1];
#pragma unroll
    for (int i = threadIdx.x; i < NSEG + 1; i += BLK) sl[i] = slices[i];
    float w[16];
#pragma unroll
    for (int i = 0; i < 16; ++i) w[i] = W[i];
    __syncthreads();

    const int base = blockIdx.x * CHUNK + threadIdx.x;
    int lo = 0, hi = NSEG;
    {
        int r0 = (base < n) ? base : (n - 1);
        while (hi - lo > 1) { int mid = (lo + hi) >> 1; if (sl[mid] <= r0) lo = mid; else hi = mid; }
    }
    int seg = lo;
    float inv = 1.0f / seg_abs[seg];
    for (int it = 0; it < RPT; ++it) {
        int r = base + it * BLK;
        if (r < n) {
            int s = seg;
            while (s < NSEG - 1 && sl[s + 1] <= r) ++s;
            if (s != seg) { seg = s; inv = 1.0f / seg_abs[seg]; }
            v4 v = x[r], o;
            o.x = (v.x * w[0]  + v.y * w[1]  + v.z * w[2]  + v.w * w[3])  * inv;
            o.y = (v.x * w[4]  + v.y * w[5]  + v.z * w[6]  + v.w * w[7])  * inv;
            o.z = (v.x * w[8]  + v.y * w[9]  + v.z * w[10] + v.w * w[11]) * inv;
            o.w = (v.x * w[12] + v.y * w[13] + v.z * w[14] + v.w * w[15]) * inv;
            __builtin_nontemporal_store(o, &out[r]);
        }
    }
}

extern "C" void kernel_launch(void* const* d_in, const int* in_sizes, int n_in,
                              void* d_out, int out_size, void* d_ws, size_t ws_size,
                              hipStream_t stream) {
    const v4*    x       = (const v4*)d_in[0];
    const int*   slices  = (const int*)d_in[1];
    const float* W       = (const float*)d_in[2];
    float*       seg_abs = (float*)d_ws;        // NSEG floats of scratch
    v4*          out     = (v4*)d_out;
    int n       = in_sizes[0] / 4;              // number of rows
    int nchunks = (n + CHUNK - 1) / CHUNK;

    // co-residency capacity for the cooperative launch (queried once)
    static int maxb = 0;
    if (maxb == 0) {
        if (hipOccupancyMaxActiveBlocksPerMultiprocessor(&maxb, seg_fused, BLK, 0)
                != hipSuccess || maxb < 1)
            maxb = 1;
    }
    int grid = nchunks < maxb * NCU ? nchunks : maxb * NCU;

    void* args[] = { (void*)&x, (void*)&slices, (void*)&W, (void*)&seg_abs,
                     (void*)&out, (void*)&n, (void*)&nchunks };
    hipError_t err = hipLaunchCooperativeKernel((const void*)seg_fused,
                                                dim3(grid), dim3(BLK),
                                                args, 0, stream);
    if (err != hipSuccess) {
        // fallback: proven two-pass path (seg_abs must be zeroed; ws is poisoned)
        hipMemsetAsync(d_ws, 0, NSEG * sizeof(float), stream);
        int nblocks = (n + CHUNK - 1) / CHUNK;
        seg_pass1<<<nblocks, BLK, 0, stream>>>(x, slices, W, seg_abs, n);
        seg_pass2<<<nblocks, BLK, 0, stream>>>(x, slices, W, seg_abs, out, n);
    }
}

// Round 2
// 261.065 us; speedup vs baseline: 1.8834x; 1.8834x over previous
//
#include <hip/hip_runtime.h>

// Segment-normalized chunked linear, two plain passes (graph-capture safe):
//   pass1: stream x (HBM), per-thread |y|-row sums accumulated per segment;
//          flush via 64-bin LDS window hist -> few global atomics per block.
//   pass2: re-stream x (L3-resident), y = x @ W.T, scale by 1/seg_abs[seg],
//          nontemporal store so the write stream doesn't evict x from L3.
//
// vs previous best (265 us): removed the 16KB slices->LDS staging, the
// 4096-bin LDS hist zero + flush scan (per-block overhead ~= streaming cost),
// and the 32KB LDS occupancy cap. Segment tracking is now a register compare
// against the cached next-boundary (slices is 16KB, L1/L2-resident).
// HBM floor ~268 MB -> ~45 us; poison fill (~80 us) is harness-owned.

#define NSEG  4096
#define BLK   256
#define RPT   32                  // rows per thread
#define BATCH 8                   // loads issued back-to-back (MLP)
#define CHUNK (BLK * RPT)         // 8192 rows per block -> 1024 blocks
#define WSZ   64                  // LDS hist window (segments); avg ~4 used

typedef float v4 __attribute__((ext_vector_type(4)));

__device__ __forceinline__ float absrow(v4 v, const float* w) {
    float y0 = fabsf(v.x * w[0]  + v.y * w[1]  + v.z * w[2]  + v.w * w[3]);
    float y1 = fabsf(v.x * w[4]  + v.y * w[5]  + v.z * w[6]  + v.w * w[7]);
    float y2 = fabsf(v.x * w[8]  + v.y * w[9]  + v.z * w[10] + v.w * w[11]);
    float y3 = fabsf(v.x * w[12] + v.y * w[13] + v.z * w[14] + v.w * w[15]);
    return (y0 + y1) + (y2 + y3);
}

__device__ __forceinline__ void flush_seg(float acc, int seg, int s0,
                                          float* hist, float* __restrict__ seg_abs) {
    if (acc == 0.0f) return;
    int d = seg - s0;
    if (d < WSZ) atomicAdd(&hist[d], acc);       // common: LDS window
    else         atomicAdd(&seg_abs[seg], acc);  // rare overflow: direct global
}

__global__ __launch_bounds__(BLK) void seg_pass1(
    const v4* __restrict__ x, const int* __restrict__ slices,
    const float* __restrict__ W, float* __restrict__ seg_abs, int n)
{
    __shared__ float hist[WSZ];
    __shared__ int s0_sh;
    if (threadIdx.x < WSZ) hist[threadIdx.x] = 0.0f;

    float w[16];
#pragma unroll
    for (int i = 0; i < 16; ++i) w[i] = W[i];

    const int base = blockIdx.x * CHUNK + threadIdx.x;

    // per-thread binary search in global slices (L1-broadcast; once per block)
    int r0 = (base < n) ? base : (n - 1);
    int lo = 0, hi = NSEG;
    while (hi - lo > 1) { int mid = (lo + hi) >> 1; if (slices[mid] <= r0) lo = mid; else hi = mid; }
    int seg = lo;
    if (threadIdx.x == 0) s0_sh = seg;           // block's first-row segment
    __syncthreads();
    const int s0 = s0_sh;

    int   nextb = slices[seg + 1];               // cached next boundary (register)
    float acc   = 0.0f;

    const bool full = (base + (RPT - 1) * BLK) < n;
    if (full) {
#pragma unroll
        for (int b = 0; b < RPT / BATCH; ++b) {
            v4 d[BATCH];
#pragma unroll
            for (int j = 0; j < BATCH; ++j)      // BATCH loads issue back-to-back
                d[j] = x[base + (b * BATCH + j) * BLK];
#pragma unroll
            for (int j = 0; j < BATCH; ++j) {
                int r = base + (b * BATCH + j) * BLK;
                if (r >= nextb) {                // register compare; loads only on advance
                    flush_seg(acc, seg, s0, hist, seg_abs);
                    acc = 0.0f;
                    do { ++seg; nextb = slices[seg + 1]; } while (r >= nextb);
                }
                acc += absrow(d[j], w);
            }
        }
    } else {
        for (int it = 0; it < RPT; ++it) {
            int r = base + it * BLK;
            if (r < n) {
                if (r >= nextb) {
                    flush_seg(acc, seg, s0, hist, seg_abs);
                    acc = 0.0f;
                    do { ++seg; nextb = slices[seg + 1]; } while (r >= nextb);
                }
                acc += absrow(x[r], w);
            }
        }
    }
    flush_seg(acc, seg, s0, hist, seg_abs);
    __syncthreads();

    if (threadIdx.x < WSZ) {
        float h = hist[threadIdx.x];
        if (h != 0.0f) atomicAdd(&seg_abs[s0 + threadIdx.x], h);
    }
}

__global__ __launch_bounds__(BLK) void seg_pass2(
    const v4* __restrict__ x, const int* __restrict__ slices,
    const float* __restrict__ W, const float* __restrict__ seg_abs,
    v4* __restrict__ out, int n)
{
    float w[16];
#pragma unroll
    for (int i = 0; i < 16; ++i) w[i] = W[i];

    const int base = blockIdx.x * CHUNK + threadIdx.x;

    int r0 = (base < n) ? base : (n - 1);
    int lo = 0, hi = NSEG;
    while (hi - lo > 1) { int mid = (lo + hi) >> 1; if (slices[mid] <= r0) lo = mid; else hi = mid; }
    int seg = lo;

    int   nextb = slices[seg + 1];
    float inv   = 1.0f / seg_abs[seg];

    const bool full = (base + (RPT - 1) * BLK) < n;
    if (full) {
#pragma unroll
        for (int b = 0; b < RPT / BATCH; ++b) {
            v4 d[BATCH];
#pragma unroll
            for (int j = 0; j < BATCH; ++j)
                d[j] = x[base + (b * BATCH + j) * BLK];
#pragma unroll
            for (int j = 0; j < BATCH; ++j) {
                int r = base + (b * BATCH + j) * BLK;
                if (r >= nextb) {
                    do { ++seg; nextb = slices[seg + 1]; } while (r >= nextb);
                    inv = 1.0f / seg_abs[seg];
                }
                v4 v = d[j], o;
                o.x = (v.x * w[0]  + v.y * w[1]  + v.z * w[2]  + v.w * w[3])  * inv;
                o.y = (v.x * w[4]  + v.y * w[5]  + v.z * w[6]  + v.w * w[7])  * inv;
                o.z = (v.x * w[8]  + v.y * w[9]  + v.z * w[10] + v.w * w[11]) * inv;
                o.w = (v.x * w[12] + v.y * w[13] + v.z * w[14] + v.w * w[15]) * inv;
                __builtin_nontemporal_store(o, &out[r]);   // keep x resident in L3
            }
        }
    } else {
        for (int it = 0; it < RPT; ++it) {
            int r = base + it * BLK;
            if (r < n) {
                if (r >= nextb) {
                    do { ++seg; nextb = slices[seg + 1]; } while (r >= nextb);
                    inv = 1.0f / seg_abs[seg];
                }
                v4 v = x[r], o;
                o.x = (v.x * w[0]  + v.y * w[1]  + v.z * w[2]  + v.w * w[3])  * inv;
                o.y = (v.x * w[4]  + v.y * w[5]  + v.z * w[6]  + v.w * w[7])  * inv;
                o.z = (v.x * w[8]  + v.y * w[9]  + v.z * w[10] + v.w * w[11]) * inv;
                o.w = (v.x * w[12] + v.y * w[13] + v.z * w[14] + v.w * w[15]) * inv;
                __builtin_nontemporal_store(o, &out[r]);
            }
        }
    }
}

extern "C" void kernel_launch(void* const* d_in, const int* in_sizes, int n_in,
                              void* d_out, int out_size, void* d_ws, size_t ws_size,
                              hipStream_t stream) {
    const v4*    x       = (const v4*)d_in[0];
    const int*   slices  = (const int*)d_in[1];
    const float* W       = (const float*)d_in[2];
    float*       seg_abs = (float*)d_ws;       // NSEG floats of scratch
    v4*          out     = (v4*)d_out;
    int n = in_sizes[0] / 4;                   // number of rows

    hipMemsetAsync(d_ws, 0, NSEG * sizeof(float), stream);  // ws is poisoned 0xAA

    int nblocks = (n + CHUNK - 1) / CHUNK;
    seg_pass1<<<nblocks, BLK, 0, stream>>>(x, slices, W, seg_abs, n);
    seg_pass2<<<nblocks, BLK, 0, stream>>>(x, slices, W, seg_abs, out, n);
}

// Round 3
// 259.425 us; speedup vs baseline: 1.8953x; 1.0063x over previous
//
#include <hip/hip_runtime.h>

// Segment-normalized chunked linear — SINGLE PASS, no workspace, no memset.
//
// Key insight: a segment's rows are CONTIGUOUS, so the normalizer for any
// row in block c's chunk depends only on rows in [slices[s_first],
// slices[s_last+1]) — a local neighborhood (~1.5x the chunk on average).
// Each block redundantly computes its overlapping segments' |y|-sums from
// that extended range (extension reads are L2/L3-shared with neighbors),
// inverts them in LDS, then normalizes + NT-stores its own chunk.
// No inter-block communication -> one plain dispatch, graph-capture safe.
//
// HBM floor: read x once (~128 MB) + write out (~128 MB) ~= 41 us.
// The ~80 us fillBufferAligned dispatches in the profile are harness poison.

#define NSEG  4096
#define BLK   256
#define RPT   32
#define CHUNK (BLK * RPT)          // 8192 rows per block -> 1024 blocks
#define WSZ   256                  // LDS bins (== BLK); avg segs/block ~5
#define NXCD  8

typedef float v4 __attribute__((ext_vector_type(4)));

__device__ __forceinline__ float absrow(v4 v, const float* w) {
    float y0 = fabsf(v.x * w[0]  + v.y * w[1]  + v.z * w[2]  + v.w * w[3]);
    float y1 = fabsf(v.x * w[4]  + v.y * w[5]  + v.z * w[6]  + v.w * w[7]);
    float y2 = fabsf(v.x * w[8]  + v.y * w[9]  + v.z * w[10] + v.w * w[11]);
    float y3 = fabsf(v.x * w[12] + v.y * w[13] + v.z * w[14] + v.w * w[15]);
    return (y0 + y1) + (y2 + y3);
}

__global__ __launch_bounds__(BLK) void seg_norm_fused(
    const v4* __restrict__ x, const int* __restrict__ slices,
    const float* __restrict__ W, v4* __restrict__ out, int n, int nblocks)
{
    __shared__ float hist[WSZ];            // partial sums -> inverses (in place)
    hist[threadIdx.x] = 0.0f;              // WSZ == BLK

    float w[16];
#pragma unroll
    for (int i = 0; i < 16; ++i) w[i] = W[i];

    // XCD-contiguous swizzle: each XCD gets a contiguous run of chunks so
    // neighbor blocks (which share extension reads) hit the same L2.
    int c = blockIdx.x;
    if ((nblocks & (NXCD - 1)) == 0) {
        int per = nblocks / NXCD;
        c = (int)(blockIdx.x & (NXCD - 1)) * per + (int)(blockIdx.x / NXCD);
    }

    const int cs = c * CHUNK;
    const int ce = (cs + CHUNK < n) ? (cs + CHUNK) : n;

    // segments overlapping this chunk (uniform across the block; slices is
    // 16 KB and L1/L2-resident, binary search = 12 broadcast hits)
    int s_first, s_last;
    {
        int lo = 0, hi = NSEG;
        while (hi - lo > 1) { int m = (lo + hi) >> 1; if (slices[m] <= cs) lo = m; else hi = m; }
        s_first = lo;
        lo = 0; hi = NSEG;
        const int rl = ce - 1;
        while (hi - lo > 1) { int m = (lo + hi) >> 1; if (slices[m] <= rl) lo = m; else hi = m; }
        s_last = lo;
    }

    // pathological fallback (more than WSZ segments in one chunk) — uniform
    // branch, correct but slow; never taken for this data distribution.
    if (s_last - s_first >= WSZ) {
        for (int r = cs + (int)threadIdx.x; r < ce; r += BLK) {
            int lo = 0, hi = NSEG;
            while (hi - lo > 1) { int m = (lo + hi) >> 1; if (slices[m] <= r) lo = m; else hi = m; }
            float ssum = 0.0f;
            const int b0 = slices[lo], b1 = slices[lo + 1];
            for (int q = b0; q < b1; ++q) ssum += absrow(x[q], w);
            const float inv = 1.0f / ssum;
            v4 v = x[r], o;
            o.x = (v.x * w[0]  + v.y * w[1]  + v.z * w[2]  + v.w * w[3])  * inv;
            o.y = (v.x * w[4]  + v.y * w[5]  + v.z * w[6]  + v.w * w[7])  * inv;
            o.z = (v.x * w[8]  + v.y * w[9]  + v.z * w[10] + v.w * w[11]) * inv;
            o.w = (v.x * w[12] + v.y * w[13] + v.z * w[14] + v.w * w[15]) * inv;
            __builtin_nontemporal_store(o, &out[r]);
        }
        return;
    }

    __syncthreads();   // hist zeros visible before any atomicAdd

    // ---- phase A: segment |y|-sums over the extended range [R0, R1) ----
    const int R0 = slices[s_first];
    const int R1 = slices[s_last + 1];     // s_last+1 <= NSEG, slices[NSEG] = n

    int   seg   = s_first;
    int   nextb = slices[seg + 1];         // cached next boundary (register)
    float acc   = 0.0f;

    int r = R0 + (int)threadIdx.x;
    for (; r + 7 * BLK < R1; r += 8 * BLK) {
        v4 d[8];
#pragma unroll
        for (int j = 0; j < 8; ++j)        // 8 loads issue back-to-back (MLP)
            d[j] = x[r + j * BLK];
#pragma unroll
        for (int j = 0; j < 8; ++j) {
            const int rr = r + j * BLK;
            if (rr >= nextb) {             // register compare; advance is rare
                if (acc != 0.0f) atomicAdd(&hist[seg - s_first], acc);
                acc = 0.0f;
                do { ++seg; nextb = slices[seg + 1]; } while (rr >= nextb);
            }
            acc += absrow(d[j], w);
        }
    }
    for (; r < R1; r += BLK) {             // remainder (extended range is
        if (r >= nextb) {                  //  not a multiple of 8*BLK)
            if (acc != 0.0f) atomicAdd(&hist[seg - s_first], acc);
            acc = 0.0f;
            do { ++seg; nextb = slices[seg + 1]; } while (r >= nextb);
        }
        acc += absrow(x[r], w);
    }
    if (acc != 0.0f) atomicAdd(&hist[seg - s_first], acc);

    // ---- phase B: invert in place ----
    __syncthreads();
    {
        const float h = hist[threadIdx.x]; // own-slot RMW, no cross-thread hazard
        hist[threadIdx.x] = (h > 0.0f) ? (1.0f / h) : 0.0f;
    }
    __syncthreads();

    // ---- phase C: normalize own chunk (x rows are L3-hot from phase A) ----
    seg   = s_first;
    nextb = slices[seg + 1];
    float inv = hist[0];

    r = cs + (int)threadIdx.x;
    for (; r + 7 * BLK < ce; r += 8 * BLK) {
        v4 d[8];
#pragma unroll
        for (int j = 0; j < 8; ++j)
            d[j] = x[r + j * BLK];
#pragma unroll
        for (int j = 0; j < 8; ++j) {
            const int rr = r + j * BLK;
            if (rr >= nextb) {
                do { ++seg; nextb = slices[seg + 1]; } while (rr >= nextb);
                inv = hist[seg - s_first];
            }
            v4 v = d[j], o;
            o.x = (v.x * w[0]  + v.y * w[1]  + v.z * w[2]  + v.w * w[3])  * inv;
            o.y = (v.x * w[4]  + v.y * w[5]  + v.z * w[6]  + v.w * w[7])  * inv;
            o.z = (v.x * w[8]  + v.y * w[9]  + v.z * w[10] + v.w * w[11]) * inv;
            o.w = (v.x * w[12] + v.y * w[13] + v.z * w[14] + v.w * w[15]) * inv;
            __builtin_nontemporal_store(o, &out[rr]);   // keep x resident in L3
        }
    }
    for (; r < ce; r += BLK) {
        if (r >= nextb) {
            do { ++seg; nextb = slices[seg + 1]; } while (r >= nextb);
            inv = hist[seg - s_first];
        }
        v4 v = x[r], o;
        o.x = (v.x * w[0]  + v.y * w[1]  + v.z * w[2]  + v.w * w[3])  * inv;
        o.y = (v.x * w[4]  + v.y * w[5]  + v.z * w[6]  + v.w * w[7])  * inv;
        o.z = (v.x * w[8]  + v.y * w[9]  + v.z * w[10] + v.w * w[11]) * inv;
        o.w = (v.x * w[12] + v.y * w[13] + v.z * w[14] + v.w * w[15]) * inv;
        __builtin_nontemporal_store(o, &out[r]);
    }
}

extern "C" void kernel_launch(void* const* d_in, const int* in_sizes, int n_in,
                              void* d_out, int out_size, void* d_ws, size_t ws_size,
                              hipStream_t stream) {
    const v4*    x      = (const v4*)d_in[0];
    const int*   slices = (const int*)d_in[1];
    const float* W      = (const float*)d_in[2];
    v4*          out    = (v4*)d_out;
    int n = in_sizes[0] / 4;               // number of rows
    int nblocks = (n + CHUNK - 1) / CHUNK; // 1024 for N=8388608

    // one plain dispatch: no workspace, no memset, no cooperative launch
    seg_norm_fused<<<nblocks, BLK, 0, stream>>>(x, slices, W, out, n, nblocks);
}

// Round 6
// 256.679 us; speedup vs baseline: 1.9156x; 1.0107x over previous
//
#include <hip/hip_runtime.h>

// Segment-normalized chunked linear — SINGLE PASS, no workspace, no memset.
//
// A segment's rows are CONTIGUOUS, so block c's normalizers depend only on
// rows [slices[s_first], slices[s_last+1]) — a local neighborhood of its
// chunk. Each block redundantly computes its segments' |y|-sums from that
// extended range (extension reads are L2/L3-shared with XCD-neighbors),
// inverts in LDS, then normalizes + NT-stores its own chunk. No inter-block
// communication -> one plain dispatch, graph-capture safe.
//
// R3 counters (CHUNK=8192, 1024 blocks): 103 us, FETCH 155 MB, WRITE 131 MB,
// 2.8 TB/s (35%), VGPR 24, Occupancy 34%. Traffic ~= the 268 MB floor; the
// limiter is wave concurrency: 4 blocks/CU = 16/32 waves. R6: halve CHUNK ->
// 2048 blocks = 8 blocks/CU = 32 waves/CU. Everything else unchanged from
// the known-good R3 build (BLK 256, no min-waves launch bound).

#define NSEG  4096
#define BLK   256
#define RPT   16
#define CHUNK (BLK * RPT)          // 4096 rows per block -> 2048 blocks
#define WSZ   256                  // LDS bins; avg segs/block ~3
#define NXCD  8

typedef float v4 __attribute__((ext_vector_type(4)));

__device__ __forceinline__ float absrow(v4 v, const float* w) {
    float y0 = fabsf(v.x * w[0]  + v.y * w[1]  + v.z * w[2]  + v.w * w[3]);
    float y1 = fabsf(v.x * w[4]  + v.y * w[5]  + v.z * w[6]  + v.w * w[7]);
    float y2 = fabsf(v.x * w[8]  + v.y * w[9]  + v.z * w[10] + v.w * w[11]);
    float y3 = fabsf(v.x * w[12] + v.y * w[13] + v.z * w[14] + v.w * w[15]);
    return (y0 + y1) + (y2 + y3);
}

__global__ __launch_bounds__(BLK) void seg_norm_fused(
    const v4* __restrict__ x, const int* __restrict__ slices,
    const float* __restrict__ W, v4* __restrict__ out, int n, int nblocks)
{
    __shared__ float hist[WSZ];            // partial sums -> inverses (in place)
    hist[threadIdx.x] = 0.0f;              // WSZ == BLK

    float w[16];
#pragma unroll
    for (int i = 0; i < 16; ++i) w[i] = W[i];

    // XCD-contiguous swizzle: each XCD gets a contiguous run of chunks so
    // neighbor blocks (which share extension reads) hit the same L2.
    int c = blockIdx.x;
    if ((nblocks & (NXCD - 1)) == 0) {
        int per = nblocks / NXCD;
        c = (int)(blockIdx.x & (NXCD - 1)) * per + (int)(blockIdx.x / NXCD);
    }

    const int cs = c * CHUNK;
    const int ce = (cs + CHUNK < n) ? (cs + CHUNK) : n;

    // segments overlapping this chunk (block-uniform; slices is 16 KB and
    // L1/L2-resident -> 12 scalar broadcast hits per search)
    int s_first, s_last;
    {
        int lo = 0, hi = NSEG;
        while (hi - lo > 1) { int m = (lo + hi) >> 1; if (slices[m] <= cs) lo = m; else hi = m; }
        s_first = lo;
        lo = 0; hi = NSEG;
        const int rl = ce - 1;
        while (hi - lo > 1) { int m = (lo + hi) >> 1; if (slices[m] <= rl) lo = m; else hi = m; }
        s_last = lo;
    }

    // pathological fallback (more than WSZ segments in one chunk) — uniform
    // branch, correct for any boundary distribution; never taken here.
    if (s_last - s_first >= WSZ) {
        for (int r = cs + (int)threadIdx.x; r < ce; r += BLK) {
            int lo = 0, hi = NSEG;
            while (hi - lo > 1) { int m = (lo + hi) >> 1; if (slices[m] <= r) lo = m; else hi = m; }
            float ssum = 0.0f;
            const int b0 = slices[lo], b1 = slices[lo + 1];
            for (int q = b0; q < b1; ++q) ssum += absrow(x[q], w);
            const float inv = 1.0f / ssum;
            v4 v = x[r], o;
            o.x = (v.x * w[0]  + v.y * w[1]  + v.z * w[2]  + v.w * w[3])  * inv;
            o.y = (v.x * w[4]  + v.y * w[5]  + v.z * w[6]  + v.w * w[7])  * inv;
            o.z = (v.x * w[8]  + v.y * w[9]  + v.z * w[10] + v.w * w[11]) * inv;
            o.w = (v.x * w[12] + v.y * w[13] + v.z * w[14] + v.w * w[15]) * inv;
            __builtin_nontemporal_store(o, &out[r]);
        }
        return;
    }

    __syncthreads();   // hist zeros visible before any atomicAdd

    // ---- phase A: segment |y|-sums over the extended range [R0, R1) ----
    const int R0 = slices[s_first];
    const int R1 = slices[s_last + 1];     // s_last+1 <= NSEG, slices[NSEG] = n

    int   seg   = s_first;
    int   nextb = slices[seg + 1];         // cached next boundary (register)
    float acc   = 0.0f;

    int r = R0 + (int)threadIdx.x;
    for (; r + 7 * BLK < R1; r += 8 * BLK) {
        v4 d[8];
#pragma unroll
        for (int j = 0; j < 8; ++j)        // loads issue ahead of consumption
            d[j] = x[r + j * BLK];
#pragma unroll
        for (int j = 0; j < 8; ++j) {
            const int rr = r + j * BLK;
            if (rr >= nextb) {             // register compare; advance is rare
                if (acc != 0.0f) atomicAdd(&hist[seg - s_first], acc);
                acc = 0.0f;
                do { ++seg; nextb = slices[seg + 1]; } while (rr >= nextb);
            }
            acc += absrow(d[j], w);
        }
    }
    for (; r < R1; r += BLK) {             // remainder
        if (r >= nextb) {
            if (acc != 0.0f) atomicAdd(&hist[seg - s_first], acc);
            acc = 0.0f;
            do { ++seg; nextb = slices[seg + 1]; } while (r >= nextb);
        }
        acc += absrow(x[r], w);
    }
    if (acc != 0.0f) atomicAdd(&hist[seg - s_first], acc);

    // ---- phase B: invert in place ----
    __syncthreads();
    {
        const float h = hist[threadIdx.x]; // own-slot RMW, no cross-thread hazard
        hist[threadIdx.x] = (h > 0.0f) ? (1.0f / h) : 0.0f;
    }
    __syncthreads();

    // ---- phase C: normalize own chunk (x rows are L2/L3-hot from phase A) ----
    seg   = s_first;
    nextb = slices[seg + 1];
    float inv = hist[0];

    r = cs + (int)threadIdx.x;
    for (; r + 7 * BLK < ce; r += 8 * BLK) {
        v4 d[8];
#pragma unroll
        for (int j = 0; j < 8; ++j)
            d[j] = x[r + j * BLK];
#pragma unroll
        for (int j = 0; j < 8; ++j) {
            const int rr = r + j * BLK;
            if (rr >= nextb) {
                do { ++seg; nextb = slices[seg + 1]; } while (rr >= nextb);
                inv = hist[seg - s_first];
            }
            v4 v = d[j], o;
            o.x = (v.x * w[0]  + v.y * w[1]  + v.z * w[2]  + v.w * w[3])  * inv;
            o.y = (v.x * w[4]  + v.y * w[5]  + v.z * w[6]  + v.w * w[7])  * inv;
            o.z = (v.x * w[8]  + v.y * w[9]  + v.z * w[10] + v.w * w[11]) * inv;
            o.w = (v.x * w[12] + v.y * w[13] + v.z * w[14] + v.w * w[15]) * inv;
            __builtin_nontemporal_store(o, &out[rr]);   // keep x resident in L3
        }
    }
    for (; r < ce; r += BLK) {
        if (r >= nextb) {
            do { ++seg; nextb = slices[seg + 1]; } while (r >= nextb);
            inv = hist[seg - s_first];
        }
        v4 v = x[r], o;
        o.x = (v.x * w[0]  + v.y * w[1]  + v.z * w[2]  + v.w * w[3])  * inv;
        o.y = (v.x * w[4]  + v.y * w[5]  + v.z * w[6]  + v.w * w[7])  * inv;
        o.z = (v.x * w[8]  + v.y * w[9]  + v.z * w[10] + v.w * w[11]) * inv;
        o.w = (v.x * w[12] + v.y * w[13] + v.z * w[14] + v.w * w[15]) * inv;
        __builtin_nontemporal_store(o, &out[r]);
    }
}

extern "C" void kernel_launch(void* const* d_in, const int* in_sizes, int n_in,
                              void* d_out, int out_size, void* d_ws, size_t ws_size,
                              hipStream_t stream) {
    const v4*    x      = (const v4*)d_in[0];
    const int*   slices = (const int*)d_in[1];
    const float* W      = (const float*)d_in[2];
    v4*          out    = (v4*)d_out;
    int n = in_sizes[0] / 4;               // number of rows
    int nblocks = (n + CHUNK - 1) / CHUNK; // 2048 for N=8388608

    // one plain dispatch: no workspace, no memset, no cooperative launch
    seg_norm_fused<<<nblocks, BLK, 0, stream>>>(x, slices, W, out, n, nblocks);
}